// Round 1
// baseline (37780.115 us; speedup 1.0000x reference)
//
#include <hip/hip_runtime.h>
#include <hip/hip_bf16.h>

#define BATCH  4096
#define NCC    64
#define HDIM   256
#define CBMD   208     // 3*NC+NT
#define G3     768     // 3*H
#define INW    209     // GRU input width
#define MLPIN  464     // H + CBMD
#define NK     20
#define LOG2PI 1.8378770664093453f

__device__ __forceinline__ float sigm(float x) { return 1.0f/(1.0f + __expf(-x)); }
__device__ __forceinline__ float tanh_fast(float x) { return 1.0f - 2.0f/(__expf(2.0f*x) + 1.0f); }

// Build cbm[B,208] = [c|b|m]; zero initial hidden state.
__global__ __launch_bounds__(256) void k_prep(const float* __restrict__ c,
    const float* __restrict__ bv, const float* __restrict__ mv,
    float* __restrict__ cbm, float* __restrict__ h0) {
  int b = blockIdx.x, tid = threadIdx.x;
  if (tid < CBMD) {
    float v;
    if (tid < 80)       v = c [b*80 + tid];
    else if (tid < 144) v = bv[b*64 + (tid-80)];
    else                v = mv[b*64 + (tid-144)];
    cbm[b*CBMD + tid] = v;
  }
  h0[b*HDIM + tid] = 0.0f;
}

// Split W_ih into w0[g]=W_ih[g][0] and Wt[g][k]=W_ih[g][1+k] (aligned rows).
__global__ __launch_bounds__(256) void k_tw(const float* __restrict__ W_ih,
    float* __restrict__ Wt, float* __restrict__ w0) {
  int idx = blockIdx.x*256 + threadIdx.x;
  if (idx >= G3*INW) return;
  int g = idx / INW;
  int k = idx - g*INW;
  float v = W_ih[idx];
  if (k == 0) w0[g] = v;
  else        Wt[g*CBMD + (k-1)] = v;
}

// gi_cbm[B,768] = cbm @ Wt^T + b_ih.  Grid = 256 row-blocks x 3 col-blocks.
__global__ __launch_bounds__(256) void k_gi(const float* __restrict__ cbm,
    const float* __restrict__ Wt, const float* __restrict__ b_ih,
    float* __restrict__ gi) {
  __shared__ __align__(16) float a_s[16][CBMD];
  int tid = threadIdx.x;
  int rb = blockIdx.x / 3, cb = blockIdx.x - rb*3;
  int row0 = rb*16, c0 = cb*256;
  for (int i = tid; i < 16*CBMD; i += 256) {
    int rr = i / CBMD, kk = i - rr*CBMD;
    a_s[rr][kk] = cbm[(row0+rr)*CBMD + kk];
  }
  __syncthreads();
  int r = tid >> 4, c16 = tid & 15;
  float acc[16];
#pragma unroll
  for (int j = 0; j < 16; ++j) acc[j] = 0.0f;
  const float4* a4 = reinterpret_cast<const float4*>(a_s[r]);
  const float4* w4 = reinterpret_cast<const float4*>(Wt);
  for (int k4 = 0; k4 < CBMD/4; ++k4) {
    float4 av = a4[k4];
#pragma unroll
    for (int j = 0; j < 16; ++j) {
      int cc = c0 + c16 + 16*j;
      float4 wv = w4[cc*(CBMD/4) + k4];
      acc[j] = fmaf(av.x, wv.x, acc[j]);
      acc[j] = fmaf(av.y, wv.y, acc[j]);
      acc[j] = fmaf(av.z, wv.z, acc[j]);
      acc[j] = fmaf(av.w, wv.w, acc[j]);
    }
  }
  int row = row0 + r;
#pragma unroll
  for (int j = 0; j < 16; ++j) {
    int cc = c0 + c16 + 16*j;
    gi[row*G3 + cc] = acc[j] + b_ih[cc];
  }
}

// One GRU step. Grid = 256 row-blocks x 4 col-blocks (64 h-dims each).
// Double-buffered h (hin -> hout) to avoid cross-block races.
__global__ __launch_bounds__(256) void k_gru(int t,
    const float* __restrict__ z, const float* __restrict__ gi,
    const float* __restrict__ W_hh, const float* __restrict__ b_hh,
    const float* __restrict__ w0, const float* __restrict__ hin,
    float* __restrict__ hout, __hip_bfloat16* __restrict__ hs) {
  __shared__ __align__(16) float h_s[16][HDIM];
  int tid = threadIdx.x;
  int rb = blockIdx.x >> 2, cb = blockIdx.x & 3;
  int row0 = rb*16, i0 = cb*64;
  for (int i = tid; i < 16*HDIM; i += 256)
    h_s[i >> 8][i & 255] = hin[row0*HDIM + i];
  __syncthreads();
  int r = tid >> 4, c16 = tid & 15;
  int row = row0 + r;
  float accr[4], accu[4], accn[4];
#pragma unroll
  for (int j = 0; j < 4; ++j) {
    int cc = i0 + c16 + 16*j;
    accr[j] = b_hh[cc];
    accu[j] = b_hh[256+cc];
    accn[j] = b_hh[512+cc];
  }
  const float4* h4 = reinterpret_cast<const float4*>(h_s[r]);
  const float4* w4 = reinterpret_cast<const float4*>(W_hh);
  for (int k4 = 0; k4 < HDIM/4; ++k4) {
    float4 hv = h4[k4];
#pragma unroll
    for (int j = 0; j < 4; ++j) {
      int cc = i0 + c16 + 16*j;
      float4 wr = w4[cc*64 + k4];
      float4 wu = w4[(256+cc)*64 + k4];
      float4 wn = w4[(512+cc)*64 + k4];
      accr[j] = fmaf(hv.x,wr.x,accr[j]); accr[j] = fmaf(hv.y,wr.y,accr[j]);
      accr[j] = fmaf(hv.z,wr.z,accr[j]); accr[j] = fmaf(hv.w,wr.w,accr[j]);
      accu[j] = fmaf(hv.x,wu.x,accu[j]); accu[j] = fmaf(hv.y,wu.y,accu[j]);
      accu[j] = fmaf(hv.z,wu.z,accu[j]); accu[j] = fmaf(hv.w,wu.w,accu[j]);
      accn[j] = fmaf(hv.x,wn.x,accn[j]); accn[j] = fmaf(hv.y,wn.y,accn[j]);
      accn[j] = fmaf(hv.z,wn.z,accn[j]); accn[j] = fmaf(hv.w,wn.w,accn[j]);
    }
  }
  float zp = (t == 0) ? -1.0f : z[row*NCC + (t-1)];
#pragma unroll
  for (int j = 0; j < 4; ++j) {
    int cc = i0 + c16 + 16*j;
    float gir = gi[row*G3 + cc]        + zp*w0[cc];
    float giu = gi[row*G3 + 256 + cc]  + zp*w0[256+cc];
    float gin = gi[row*G3 + 512 + cc]  + zp*w0[512+cc];
    float rr = sigm(gir + accr[j]);
    float uu = sigm(giu + accu[j]);
    float nn = tanh_fast(gin + rr*accn[j]);
    float hn = (1.0f - uu)*nn + uu*h_s[r][cc];
    hout[row*HDIM + cc] = hn;
    hs[((size_t)row*NCC + t)*HDIM + cc] = __float2bfloat16(hn);
  }
}

// Fused MLP1+MLP2+MLP3+mixture log-likelihood. 16 rows per block.
__global__ __launch_bounds__(256) void k_mlp(
    const __hip_bfloat16* __restrict__ hs, const float* __restrict__ cbm,
    const float* __restrict__ W1, const float* __restrict__ b1,
    const float* __restrict__ W2, const float* __restrict__ b2,
    const float* __restrict__ W3, const float* __restrict__ b3,
    const float* __restrict__ z, float* __restrict__ log_like) {
  __shared__ __align__(16) float feat_s[16][MLPIN];  // reused for params later
  __shared__ __align__(16) float h1_s[16][HDIM];
  __shared__ __align__(16) float h2_s[16][HDIM];
  int tid = threadIdx.x;
  size_t row0 = (size_t)blockIdx.x * 16;
  for (int i = tid; i < 16*MLPIN; i += 256) {
    int rr = i / MLPIN, kk = i - rr*MLPIN;
    size_t grow = row0 + rr;
    int bb = (int)(grow >> 6);
    float v;
    if (kk < HDIM) v = __bfloat162float(hs[grow*HDIM + kk]);
    else           v = cbm[bb*CBMD + (kk - HDIM)];
    feat_s[rr][kk] = v;
  }
  __syncthreads();
  int r = tid >> 4, c16 = tid & 15;
  // ---- MLP1: h1 = tanh(feat @ W1^T + b1), K=464 ----
  {
    float acc[16];
#pragma unroll
    for (int j = 0; j < 16; ++j) acc[j] = 0.0f;
    const float4* a4 = reinterpret_cast<const float4*>(feat_s[r]);
    const float4* w4 = reinterpret_cast<const float4*>(W1);
    for (int k4 = 0; k4 < MLPIN/4; ++k4) {
      float4 av = a4[k4];
#pragma unroll
      for (int j = 0; j < 16; ++j) {
        int cc = c16 + 16*j;
        float4 wv = w4[cc*(MLPIN/4) + k4];
        acc[j] = fmaf(av.x, wv.x, acc[j]);
        acc[j] = fmaf(av.y, wv.y, acc[j]);
        acc[j] = fmaf(av.z, wv.z, acc[j]);
        acc[j] = fmaf(av.w, wv.w, acc[j]);
      }
    }
#pragma unroll
    for (int j = 0; j < 16; ++j) {
      int cc = c16 + 16*j;
      h1_s[r][cc] = tanh_fast(acc[j] + b1[cc]);
    }
  }
  __syncthreads();
  // ---- MLP2: h2 = tanh(h1 @ W2^T + b2), K=256 ----
  {
    float acc[16];
#pragma unroll
    for (int j = 0; j < 16; ++j) acc[j] = 0.0f;
    const float4* a4 = reinterpret_cast<const float4*>(h1_s[r]);
    const float4* w4 = reinterpret_cast<const float4*>(W2);
    for (int k4 = 0; k4 < HDIM/4; ++k4) {
      float4 av = a4[k4];
#pragma unroll
      for (int j = 0; j < 16; ++j) {
        int cc = c16 + 16*j;
        float4 wv = w4[cc*(HDIM/4) + k4];
        acc[j] = fmaf(av.x, wv.x, acc[j]);
        acc[j] = fmaf(av.y, wv.y, acc[j]);
        acc[j] = fmaf(av.z, wv.z, acc[j]);
        acc[j] = fmaf(av.w, wv.w, acc[j]);
      }
    }
#pragma unroll
    for (int j = 0; j < 16; ++j) {
      int cc = c16 + 16*j;
      h2_s[r][cc] = tanh_fast(acc[j] + b2[cc]);
    }
  }
  __syncthreads();
  // ---- MLP3: params = h2 @ W3^T + b3 (60 cols), into feat_s alias ----
  float* params_s = &feat_s[0][0];   // [16][64] layout
  {
#pragma unroll
    for (int j = 0; j < 4; ++j) {
      int cc = c16 + 16*j;
      if (cc < 60) {
        float acc = 0.0f;
        const float4* a4 = reinterpret_cast<const float4*>(h2_s[r]);
        const float4* w4 = reinterpret_cast<const float4*>(W3 + cc*HDIM);
        for (int k4 = 0; k4 < HDIM/4; ++k4) {
          float4 av = a4[k4]; float4 wv = w4[k4];
          acc = fmaf(av.x, wv.x, acc);
          acc = fmaf(av.y, wv.y, acc);
          acc = fmaf(av.z, wv.z, acc);
          acc = fmaf(av.w, wv.w, acc);
        }
        params_s[r*64 + cc] = acc + b3[cc];
      }
    }
  }
  __syncthreads();
  // ---- mixture log-likelihood per row ----
  if (tid < 16) {
    size_t grow = row0 + tid;
    int bb = (int)(grow >> 6), tt = (int)(grow & 63);
    float zv = z[bb*NCC + tt];
    const float* p = &params_s[tid*64];
    float mx1 = -1e30f;
#pragma unroll
    for (int i = 0; i < NK; ++i) mx1 = fmaxf(mx1, p[i]);
    float s1 = 0.0f;
#pragma unroll
    for (int i = 0; i < NK; ++i) s1 += __expf(p[i] - mx1);
    float lse1 = mx1 + __logf(s1);
    float a[NK];
    float mx2 = -1e30f;
#pragma unroll
    for (int i = 0; i < NK; ++i) {
      float lg = p[i], me = p[20+i], ls = p[40+i];
      float e = __expf(-ls);
      float d = (zv - me) * e;
      float ai = -0.5f*d*d - ls - 0.5f*LOG2PI + lg;
      a[i] = ai;
      mx2 = fmaxf(mx2, ai);
    }
    float s2 = 0.0f;
#pragma unroll
    for (int i = 0; i < NK; ++i) s2 += __expf(a[i] - mx2);
    float lse2 = mx2 + __logf(s2);
    log_like[grow] = lse2 - lse1;
  }
}

// out[b] = sum_{t < S_b} log_like[b,t], S_b = #{j: m=1 & b=0}. One wave per row.
__global__ __launch_bounds__(256) void k_final(const float* __restrict__ bv,
    const float* __restrict__ mv, const float* __restrict__ log_like,
    float* __restrict__ out) {
  int tid = threadIdx.x;
  int wave = tid >> 6, lane = tid & 63;
  int b = blockIdx.x*4 + wave;
  float q = mv[b*64 + lane] * (1.0f - bv[b*64 + lane]);
  unsigned long long bal = __ballot(q > 0.5f);
  int S = __popcll(bal);
  float val = (lane < S) ? log_like[(size_t)b*64 + lane] : 0.0f;
#pragma unroll
  for (int off = 32; off > 0; off >>= 1) val += __shfl_down(val, off);
  if (lane == 0) out[b] = val;
}

extern "C" void kernel_launch(void* const* d_in, const int* in_sizes, int n_in,
                              void* d_out, int out_size, void* d_ws, size_t ws_size,
                              hipStream_t stream) {
  const float* z    = (const float*)d_in[0];
  const float* c    = (const float*)d_in[1];
  const float* bv   = (const float*)d_in[2];
  const float* mv   = (const float*)d_in[3];
  const float* W_ih = (const float*)d_in[4];
  const float* W_hh = (const float*)d_in[5];
  const float* b_ih = (const float*)d_in[6];
  const float* b_hh = (const float*)d_in[7];
  const float* W1   = (const float*)d_in[8];
  const float* b1   = (const float*)d_in[9];
  const float* W2   = (const float*)d_in[10];
  const float* b2   = (const float*)d_in[11];
  const float* W3   = (const float*)d_in[12];
  const float* b3   = (const float*)d_in[13];
  float* out = (float*)d_out;

  char* p = (char*)d_ws;
  auto alloc = [&](size_t bytes) {
    char* q = p;
    p += (bytes + 255) & ~(size_t)255;
    return q;
  };
  float* cbm = (float*)alloc((size_t)BATCH*CBMD*4);
  float* gi  = (float*)alloc((size_t)BATCH*G3*4);
  float* hA  = (float*)alloc((size_t)BATCH*HDIM*4);
  float* hB  = (float*)alloc((size_t)BATCH*HDIM*4);
  float* Wt  = (float*)alloc((size_t)G3*CBMD*4);
  float* w0  = (float*)alloc((size_t)G3*4);
  float* ll  = (float*)alloc((size_t)BATCH*NCC*4);
  __hip_bfloat16* hs = (__hip_bfloat16*)alloc((size_t)BATCH*NCC*HDIM*2);

  k_prep<<<BATCH, 256, 0, stream>>>(c, bv, mv, cbm, hA);
  k_tw<<<(G3*INW + 255)/256, 256, 0, stream>>>(W_ih, Wt, w0);
  k_gi<<<256*3, 256, 0, stream>>>(cbm, Wt, b_ih, gi);
  for (int t = 0; t < NCC; ++t) {
    const float* hin = (t & 1) ? hB : hA;
    float*       ho  = (t & 1) ? hA : hB;
    k_gru<<<256*4, 256, 0, stream>>>(t, z, gi, W_hh, b_hh, w0, hin, ho, hs);
  }
  k_mlp<<<(BATCH*NCC)/16, 256, 0, stream>>>(hs, cbm, W1, b1, W2, b2, W3, b3, z, ll);
  k_final<<<BATCH/4, 256, 0, stream>>>(bv, mv, ll, out);
}

// Round 3
// 1323.169 us; speedup vs baseline: 28.5527x; 28.5527x over previous
//
#include <hip/hip_runtime.h>
#include <hip/hip_bf16.h>

#define BATCH  4096
#define NCC    64
#define HDIM   256
#define CBMD   208     // 3*NC+NT
#define G3     768     // 3*H
#define NROW   (BATCH*NCC)   // 262144
#define NK     20
#define LOG2PI 1.8378770664093453f

typedef __attribute__((ext_vector_type(8))) short bf16x8;
typedef __attribute__((ext_vector_type(4))) float f32x4;

__device__ __forceinline__ float sigm(float x) { return 1.0f/(1.0f + __expf(-x)); }
__device__ __forceinline__ float tanh_fast(float x) { return 1.0f - 2.0f/(__expf(2.0f*x) + 1.0f); }
__device__ __forceinline__ unsigned short f2bf(float x) {
  __hip_bfloat16 h = __float2bfloat16(x);
  return __builtin_bit_cast(unsigned short, h);
}

// ---------------- prep: cbm = [c|b|m], h0 zeros (bf16 + fp32) ----------------
__global__ __launch_bounds__(256) void k_prep(const float* __restrict__ c,
    const float* __restrict__ bv, const float* __restrict__ mv,
    float* __restrict__ cbm, unsigned short* __restrict__ h0b,
    float* __restrict__ h0f) {
  int b = blockIdx.x, tid = threadIdx.x;
  if (tid < CBMD) {
    float v;
    if (tid < 80)       v = c [b*80 + tid];
    else if (tid < 144) v = bv[b*64 + (tid-80)];
    else                v = mv[b*64 + (tid-144)];
    cbm[b*CBMD + tid] = v;
  }
  h0b[b*HDIM + tid] = 0;
  h0f[b*HDIM + tid] = 0.0f;
}

// Split W_ih -> Wt[768][208] (cols 1..208) and w0[768] (col 0), fp32.
__global__ __launch_bounds__(256) void k_tw(const float* __restrict__ W_ih,
    float* __restrict__ Wt, float* __restrict__ w0) {
  int idx = blockIdx.x*256 + threadIdx.x;
  if (idx >= G3*209) return;
  int g = idx / 209;
  int k = idx - g*209;
  float v = W_ih[idx];
  if (k == 0) w0[g] = v;
  else        Wt[g*CBMD + (k-1)] = v;
}

// Convert weights to bf16.
__global__ __launch_bounds__(256) void k_cvt(const float* __restrict__ Whh,
    const float* __restrict__ W1, const float* __restrict__ W2,
    const float* __restrict__ W3, unsigned short* __restrict__ WhhB,
    unsigned short* __restrict__ W1aB, unsigned short* __restrict__ W2B,
    unsigned short* __restrict__ W3pB) {
  int idx = blockIdx.x*256 + threadIdx.x;
  if (idx < 196608) { WhhB[idx] = f2bf(Whh[idx]); return; }
  idx -= 196608;
  if (idx < 65536) { int n = idx>>8, k = idx&255; W1aB[idx] = f2bf(W1[n*464+k]); return; }
  idx -= 65536;
  if (idx < 65536) { W2B[idx] = f2bf(W2[idx]); return; }
  idx -= 65536;
  if (idx < 16384) {
    int n = idx>>8;
    if (n < 60) W3pB[idx] = f2bf(W3[idx]);   // explicit branch: no OOB speculation
    else        W3pB[idx] = 0;
  }
}

// gi = cbm @ Wt^T + b_ih  [4096,768] fp32. Grid 256 rb x 3 cb.
__global__ __launch_bounds__(256) void k_gi(const float* __restrict__ cbm,
    const float* __restrict__ Wt, const float* __restrict__ b_ih,
    float* __restrict__ gi) {
  __shared__ __align__(16) float a_s[16][CBMD];
  int tid = threadIdx.x;
  int rb = blockIdx.x / 3, cb = blockIdx.x - rb*3;
  int row0 = rb*16, c0 = cb*256;
  for (int i = tid; i < 16*CBMD; i += 256) {
    int rr = i / CBMD, kk = i - rr*CBMD;
    a_s[rr][kk] = cbm[(row0+rr)*CBMD + kk];
  }
  __syncthreads();
  int r = tid >> 4, c16 = tid & 15;
  float acc[16];
#pragma unroll
  for (int j = 0; j < 16; ++j) acc[j] = 0.0f;
  const float4* a4 = reinterpret_cast<const float4*>(a_s[r]);
  const float4* w4 = reinterpret_cast<const float4*>(Wt);
  for (int k4 = 0; k4 < CBMD/4; ++k4) {
    float4 av = a4[k4];
#pragma unroll
    for (int j = 0; j < 16; ++j) {
      int cc = c0 + c16 + 16*j;
      float4 wv = w4[cc*(CBMD/4) + k4];
      acc[j] = fmaf(av.x, wv.x, acc[j]);
      acc[j] = fmaf(av.y, wv.y, acc[j]);
      acc[j] = fmaf(av.z, wv.z, acc[j]);
      acc[j] = fmaf(av.w, wv.w, acc[j]);
    }
  }
  int row = row0 + r;
#pragma unroll
  for (int j = 0; j < 16; ++j) {
    int cc = c0 + c16 + 16*j;
    gi[row*G3 + cc] = acc[j] + b_ih[cc];
  }
}

// P1 = cbm @ W1[:,256:]^T + b1  [4096,256] fp32. Grid 256.
__global__ __launch_bounds__(256) void k_p1(const float* __restrict__ cbm,
    const float* __restrict__ W1, const float* __restrict__ b1,
    float* __restrict__ P1) {
  __shared__ __align__(16) float a_s[16][CBMD];
  int tid = threadIdx.x;
  int row0 = blockIdx.x*16;
  for (int i = tid; i < 16*CBMD; i += 256) {
    int rr = i / CBMD, kk = i - rr*CBMD;
    a_s[rr][kk] = cbm[(row0+rr)*CBMD + kk];
  }
  __syncthreads();
  int r = tid >> 4, c16 = tid & 15;
  float acc[16];
#pragma unroll
  for (int j = 0; j < 16; ++j) acc[j] = 0.0f;
  const float4* a4 = reinterpret_cast<const float4*>(a_s[r]);
  for (int k4 = 0; k4 < CBMD/4; ++k4) {
    float4 av = a4[k4];
#pragma unroll
    for (int j = 0; j < 16; ++j) {
      int cc = c16 + 16*j;
      float4 wv = *reinterpret_cast<const float4*>(&W1[cc*464 + 256 + k4*4]);
      acc[j] = fmaf(av.x, wv.x, acc[j]);
      acc[j] = fmaf(av.y, wv.y, acc[j]);
      acc[j] = fmaf(av.z, wv.z, acc[j]);
      acc[j] = fmaf(av.w, wv.w, acc[j]);
    }
  }
  int row = row0 + r;
#pragma unroll
  for (int j = 0; j < 16; ++j) {
    int cc = c16 + 16*j;
    P1[row*256 + cc] = acc[j] + b1[cc];
  }
}

// -------- GRU step, MFMA. Block: 64 rows x 192 gate-cols (64 h-dims). --------
__global__ __launch_bounds__(256) void k_gru(int t,
    const float* __restrict__ z, const float* __restrict__ gi,
    const unsigned short* __restrict__ Whh,   // [768][256] bf16
    const float* __restrict__ b_hh, const float* __restrict__ w0,
    const unsigned short* __restrict__ hprevb, // [4096][256] bf16
    const float* __restrict__ hprevf,          // [4096][256] fp32 master
    unsigned short* __restrict__ hnextb, float* __restrict__ hnextf,
    unsigned short* __restrict__ hs) {
  __shared__ __align__(16) unsigned short As[64*64];
  __shared__ __align__(16) unsigned short Bs[192*64];
  int tid = threadIdx.x;
  int rb = blockIdx.x >> 2, cbq = blockIdx.x & 3;
  int row0 = rb * 64;
  int c0 = cbq * 64;
  int wv = tid >> 6, lane = tid & 63;
  int lq = lane >> 4, l16 = lane & 15;
  f32x4 acc[12];
#pragma unroll
  for (int i = 0; i < 12; ++i) acc[i] = (f32x4){0.f,0.f,0.f,0.f};
  for (int kb = 0; kb < 256; kb += 64) {
#pragma unroll
    for (int i = 0; i < 2; ++i) {
      int s = i*256 + tid;
      int r = s >> 3, cg = (s & 7) ^ (r & 7);
      *(uint4*)&As[s*8] = *(const uint4*)&hprevb[(long)(row0+r)*256 + kb + cg*8];
    }
#pragma unroll
    for (int i = 0; i < 6; ++i) {
      int s = i*256 + tid;
      int r = s >> 3, cg = (s & 7) ^ (r & 7);
      int g = r >> 6, ci = r & 63;
      *(uint4*)&Bs[s*8] = *(const uint4*)&Whh[(long)(g*256 + c0 + ci)*256 + kb + cg*8];
    }
    __syncthreads();
#pragma unroll
    for (int kc = 0; kc < 2; ++kc) {
      int csel = kc*4 + lq;
      int ra = wv*16 + l16;
      bf16x8 af = *(const bf16x8*)&As[ra*64 + ((csel ^ (ra & 7)))*8];
#pragma unroll
      for (int i = 0; i < 12; ++i) {
        int rbr = i*16 + l16;
        bf16x8 bfr = *(const bf16x8*)&Bs[rbr*64 + ((csel ^ (rbr & 7)))*8];
        acc[i] = __builtin_amdgcn_mfma_f32_16x16x32_bf16(af, bfr, acc[i], 0, 0, 0);
      }
    }
    __syncthreads();
  }
  int rbase = row0 + wv*16 + lq*4;
  int tm = (t > 0) ? (t - 1) : 0;     // always-in-bounds index
  float zp[4];
#pragma unroll
  for (int q = 0; q < 4; ++q) {
    float zv = z[(rbase+q)*64 + tm];
    zp[q] = (t == 0) ? -1.0f : zv;
  }
#pragma unroll
  for (int ct = 0; ct < 4; ++ct) {
    int hcol = c0 + ct*16 + l16;
    float w0r = w0[hcol], w0u = w0[256+hcol], w0n = w0[512+hcol];
    float bhr = b_hh[hcol], bhu = b_hh[256+hcol], bhn = b_hh[512+hcol];
#pragma unroll
    for (int q = 0; q < 4; ++q) {
      int row = rbase + q;
      const float* gir = gi + (long)row*G3;
      float rr = sigm(gir[hcol]     + zp[q]*w0r + acc[ct][q]   + bhr);
      float uu = sigm(gir[256+hcol] + zp[q]*w0u + acc[4+ct][q] + bhu);
      float nn = tanh_fast(gir[512+hcol] + zp[q]*w0n + rr*(acc[8+ct][q] + bhn));
      float ho = hprevf[(long)row*256 + hcol];
      float hn = (1.0f - uu)*nn + uu*ho;
      unsigned short hb = f2bf(hn);
      hnextf[(long)row*256 + hcol] = hn;
      hnextb[(long)row*256 + hcol] = hb;
      hs[((long)row*64 + t)*256 + hcol] = hb;
    }
  }
}

// ---- In-place GEMM: Out = tanh(A[NROW,256] @ Bw[256,256]^T + bias) ----
// Block owns 128 rows x ALL 256 cols (8 waves) -> Out may alias A.
// biasMode 0: bias[n]; 1: bias[(row>>6)*256+n]. Grid: NROW/128.
__global__ __launch_bounds__(512) void k_gemm_tanh(
    const unsigned short* __restrict__ A, const unsigned short* __restrict__ Bw,
    const float* __restrict__ bias, int biasMode,
    unsigned short* __restrict__ Out) {
  __shared__ __align__(16) unsigned short As[128*64];
  __shared__ __align__(16) unsigned short Bs[256*64];
  int tid = threadIdx.x;
  long row0 = (long)blockIdx.x * 128;
  int wv = tid >> 6, lane = tid & 63;
  int lq = lane >> 4, l16 = lane & 15;
  int wrg = wv & 3, wcg = wv >> 2;  // 4 row-groups x 2 col-groups
  f32x4 acc[2][8];
#pragma unroll
  for (int i = 0; i < 2; ++i)
#pragma unroll
    for (int j = 0; j < 8; ++j) acc[i][j] = (f32x4){0.f,0.f,0.f,0.f};
  for (int kb = 0; kb < 256; kb += 64) {
#pragma unroll
    for (int i = 0; i < 2; ++i) {
      int s = i*512 + tid;
      int r = s >> 3, cg = (s & 7) ^ (r & 7);
      *(uint4*)&As[s*8] = *(const uint4*)&A[(row0 + r)*256 + kb + cg*8];
    }
#pragma unroll
    for (int i = 0; i < 4; ++i) {
      int s = i*512 + tid;
      int r = s >> 3, cg = (s & 7) ^ (r & 7);
      *(uint4*)&Bs[s*8] = *(const uint4*)&Bw[(long)r*256 + kb + cg*8];
    }
    __syncthreads();
#pragma unroll
    for (int kc = 0; kc < 2; ++kc) {
      int csel = kc*4 + lq;
      bf16x8 af[2];
#pragma unroll
      for (int rt = 0; rt < 2; ++rt) {
        int r = wrg*32 + rt*16 + l16;
        af[rt] = *(const bf16x8*)&As[r*64 + ((csel ^ (r & 7)))*8];
      }
#pragma unroll
      for (int ct = 0; ct < 8; ++ct) {
        int n = wcg*128 + ct*16 + l16;
        bf16x8 bfr = *(const bf16x8*)&Bs[n*64 + ((csel ^ (n & 7)))*8];
        acc[0][ct] = __builtin_amdgcn_mfma_f32_16x16x32_bf16(af[0], bfr, acc[0][ct], 0, 0, 0);
        acc[1][ct] = __builtin_amdgcn_mfma_f32_16x16x32_bf16(af[1], bfr, acc[1][ct], 0, 0, 0);
      }
    }
    __syncthreads();
  }
#pragma unroll
  for (int rt = 0; rt < 2; ++rt) {
#pragma unroll
    for (int q = 0; q < 4; ++q) {
      long row = row0 + wrg*32 + rt*16 + lq*4 + q;
#pragma unroll
      for (int ct = 0; ct < 8; ++ct) {
        int n = wcg*128 + ct*16 + l16;
        float b = biasMode ? bias[(row>>6)*256 + n] : bias[n];
        Out[row*256 + n] = f2bf(tanh_fast(acc[rt][ct][q] + b));
      }
    }
  }
}

// ---- MLP3 + mixture likelihood: params = h2 @ W3p^T + b3; ll per row ----
__global__ __launch_bounds__(256) void k_h3(
    const unsigned short* __restrict__ A, const unsigned short* __restrict__ W3p,
    const float* __restrict__ b3, const float* __restrict__ z,
    float* __restrict__ ll) {
  __shared__ __align__(16) unsigned short As[128*64];
  __shared__ __align__(16) unsigned short Bs[64*64];
  __shared__ __align__(16) float Ps[4][32][65];
  int tid = threadIdx.x;
  long row0 = (long)blockIdx.x * 128;
  int wv = tid >> 6, lane = tid & 63;
  int lq = lane >> 4, l16 = lane & 15;
  f32x4 acc[2][4];
#pragma unroll
  for (int i = 0; i < 2; ++i)
#pragma unroll
    for (int j = 0; j < 4; ++j) acc[i][j] = (f32x4){0.f,0.f,0.f,0.f};
  for (int kb = 0; kb < 256; kb += 64) {
#pragma unroll
    for (int i = 0; i < 4; ++i) {
      int s = i*256 + tid;
      int r = s >> 3, cg = (s & 7) ^ (r & 7);
      *(uint4*)&As[s*8] = *(const uint4*)&A[(row0 + r)*256 + kb + cg*8];
    }
#pragma unroll
    for (int i = 0; i < 2; ++i) {
      int s = i*256 + tid;
      int r = s >> 3, cg = (s & 7) ^ (r & 7);
      *(uint4*)&Bs[s*8] = *(const uint4*)&W3p[(long)r*256 + kb + cg*8];
    }
    __syncthreads();
#pragma unroll
    for (int kc = 0; kc < 2; ++kc) {
      int csel = kc*4 + lq;
      bf16x8 af[2], bfr[4];
#pragma unroll
      for (int rt = 0; rt < 2; ++rt) {
        int r = wv*32 + rt*16 + l16;
        af[rt] = *(const bf16x8*)&As[r*64 + ((csel ^ (r & 7)))*8];
      }
#pragma unroll
      for (int ct = 0; ct < 4; ++ct) {
        int r = ct*16 + l16;
        bfr[ct] = *(const bf16x8*)&Bs[r*64 + ((csel ^ (r & 7)))*8];
      }
#pragma unroll
      for (int rt = 0; rt < 2; ++rt)
#pragma unroll
        for (int ct = 0; ct < 4; ++ct)
          acc[rt][ct] = __builtin_amdgcn_mfma_f32_16x16x32_bf16(af[rt], bfr[ct], acc[rt][ct], 0, 0, 0);
    }
    __syncthreads();
  }
#pragma unroll
  for (int rt = 0; rt < 2; ++rt)
#pragma unroll
    for (int q = 0; q < 4; ++q) {
      int lrow = rt*16 + lq*4 + q;
#pragma unroll
      for (int ct = 0; ct < 4; ++ct) {
        int n = ct*16 + l16;
        Ps[wv][lrow][n] = acc[rt][ct][q] + ((n < 60) ? b3[n] : 0.0f);
      }
    }
  __syncthreads();
  if (lane < 32) {
    int lrow = lane;
    long grow = row0 + wv*32 + lrow;
    float zv = z[grow];    // z[b][t] with grow = b*64+t
    const float* p = Ps[wv][lrow];
    float mx1 = -1e30f;
#pragma unroll
    for (int i = 0; i < NK; ++i) mx1 = fmaxf(mx1, p[i]);
    float s1 = 0.0f;
#pragma unroll
    for (int i = 0; i < NK; ++i) s1 += __expf(p[i] - mx1);
    float lse1 = mx1 + __logf(s1);
    float a[NK];
    float mx2 = -1e30f;
#pragma unroll
    for (int i = 0; i < NK; ++i) {
      float lg = p[i], me = p[20+i], ls = p[40+i];
      float e = __expf(-ls);
      float d = (zv - me) * e;
      float ai = -0.5f*d*d - ls - 0.5f*LOG2PI + lg;
      a[i] = ai;
      mx2 = fmaxf(mx2, ai);
    }
    float s2 = 0.0f;
#pragma unroll
    for (int i = 0; i < NK; ++i) s2 += __expf(a[i] - mx2);
    float lse2 = mx2 + __logf(s2);
    ll[grow] = lse2 - lse1;
  }
}

// out[b] = sum_{t < S_b} ll[b,t]
__global__ __launch_bounds__(256) void k_final(const float* __restrict__ bv,
    const float* __restrict__ mv, const float* __restrict__ ll,
    float* __restrict__ out) {
  int tid = threadIdx.x;
  int wave = tid >> 6, lane = tid & 63;
  int b = blockIdx.x*4 + wave;
  float q = mv[b*64 + lane] * (1.0f - bv[b*64 + lane]);
  unsigned long long bal = __ballot(q > 0.5f);
  int S = __popcll(bal);
  float val = (lane < S) ? ll[(long)b*64 + lane] : 0.0f;
#pragma unroll
  for (int off = 32; off > 0; off >>= 1) val += __shfl_down(val, off);
  if (lane == 0) out[b] = val;
}

extern "C" void kernel_launch(void* const* d_in, const int* in_sizes, int n_in,
                              void* d_out, int out_size, void* d_ws, size_t ws_size,
                              hipStream_t stream) {
  const float* z    = (const float*)d_in[0];
  const float* c    = (const float*)d_in[1];
  const float* bv   = (const float*)d_in[2];
  const float* mv   = (const float*)d_in[3];
  const float* W_ih = (const float*)d_in[4];
  const float* W_hh = (const float*)d_in[5];
  const float* b_ih = (const float*)d_in[6];
  const float* b_hh = (const float*)d_in[7];
  const float* W1   = (const float*)d_in[8];
  const float* b1   = (const float*)d_in[9];
  const float* W2   = (const float*)d_in[10];
  const float* b2   = (const float*)d_in[11];
  const float* W3   = (const float*)d_in[12];
  const float* b3   = (const float*)d_in[13];
  float* out = (float*)d_out;

  char* p = (char*)d_ws;
  auto alloc = [&](size_t bytes) {
    char* q = p;
    p += (bytes + 255) & ~(size_t)255;
    return q;
  };
  // Total ~169.4 MB (hs dominates at 134 MB; no second activation buffer).
  float* cbm = (float*)alloc((size_t)BATCH*CBMD*4);
  float* gi  = (float*)alloc((size_t)BATCH*G3*4);
  float* Wt  = (float*)alloc((size_t)G3*CBMD*4);
  float* w0  = (float*)alloc((size_t)G3*4);
  float* P1  = (float*)alloc((size_t)BATCH*256*4);
  unsigned short* WhhB = (unsigned short*)alloc((size_t)G3*256*2);
  unsigned short* W1aB = (unsigned short*)alloc((size_t)256*256*2);
  unsigned short* W2B  = (unsigned short*)alloc((size_t)256*256*2);
  unsigned short* W3pB = (unsigned short*)alloc((size_t)64*256*2);
  unsigned short* hAb  = (unsigned short*)alloc((size_t)BATCH*HDIM*2);
  unsigned short* hBb  = (unsigned short*)alloc((size_t)BATCH*HDIM*2);
  float* hAf = (float*)alloc((size_t)BATCH*HDIM*4);
  float* hBf = (float*)alloc((size_t)BATCH*HDIM*4);
  float* ll  = (float*)alloc((size_t)NROW*4);
  unsigned short* hs = (unsigned short*)alloc((size_t)NROW*HDIM*2);

  k_prep<<<BATCH, 256, 0, stream>>>(c, bv, mv, cbm, hAb, hAf);
  k_tw<<<(G3*209 + 255)/256, 256, 0, stream>>>(W_ih, Wt, w0);
  k_cvt<<<1344, 256, 0, stream>>>(W_hh, W1, W2, W3, WhhB, W1aB, W2B, W3pB);
  k_gi<<<256*3, 256, 0, stream>>>(cbm, Wt, b_ih, gi);
  k_p1<<<256, 256, 0, stream>>>(cbm, W1, b1, P1);
  for (int t = 0; t < NCC; ++t) {
    const unsigned short* hib = (t & 1) ? hBb : hAb;
    unsigned short*       hob = (t & 1) ? hAb : hBb;
    const float*          hif = (t & 1) ? hBf : hAf;
    float*                hof = (t & 1) ? hAf : hBf;
    k_gru<<<256, 256, 0, stream>>>(t, z, gi, WhhB, b_hh, w0, hib, hif, hob, hof, hs);
  }
  // In-place MLP: hs -> hs -> hs
  k_gemm_tanh<<<NROW/128, 512, 0, stream>>>(hs, W1aB, P1, 1, hs);
  k_gemm_tanh<<<NROW/128, 512, 0, stream>>>(hs, W2B, b2, 0, hs);
  k_h3<<<NROW/128, 256, 0, stream>>>(hs, W3pB, b3, z, ll);
  k_final<<<BATCH/4, 256, 0, stream>>>(bv, mv, ll, out);
}

// Round 4
// 528.844 us; speedup vs baseline: 71.4390x; 2.5020x over previous
//
#include <hip/hip_runtime.h>
#include <hip/hip_bf16.h>

#define BATCH  4096
#define NCC    64
#define HDIM   256
#define G3     768
#define NROW   (BATCH*NCC)   // 262144
#define NK     20
#define LOG2PI 1.8378770664093453f

typedef __attribute__((ext_vector_type(8))) short bf16x8;
typedef __attribute__((ext_vector_type(4))) float f32x4;

__device__ __forceinline__ float sigm(float x) { return 1.0f/(1.0f + __expf(-x)); }
__device__ __forceinline__ float tanh_fast(float x) { return 1.0f - 2.0f/(__expf(2.0f*x) + 1.0f); }
__device__ __forceinline__ unsigned short f2bf(float x) {
  __hip_bfloat16 h = __float2bfloat16(x);
  return __builtin_bit_cast(unsigned short, h);
}

// ---- one elementwise pass: build cbmB, CW, WhhB, W1aB, W2B, W3pB, w0 ----
__global__ __launch_bounds__(256) void k_cvtall(
    const float* __restrict__ c, const float* __restrict__ bv,
    const float* __restrict__ mv, const float* __restrict__ W_ih,
    const float* __restrict__ W_hh, const float* __restrict__ W1,
    const float* __restrict__ W2, const float* __restrict__ W3,
    unsigned short* __restrict__ cbmB, unsigned short* __restrict__ CW,
    unsigned short* __restrict__ WhhB, unsigned short* __restrict__ W1aB,
    unsigned short* __restrict__ W2B, unsigned short* __restrict__ W3pB,
    float* __restrict__ w0) {
  int idx = blockIdx.x*256 + threadIdx.x;
  if (idx < 1048576) {            // cbmB [4096][256], K-padded
    int row = idx >> 8, k = idx & 255;
    float v = 0.f;
    if (k < 80)       v = c [row*80 + k];
    else if (k < 144) v = bv[row*64 + (k-80)];
    else if (k < 208) v = mv[row*64 + (k-144)];
    cbmB[idx] = f2bf(v);
    return;
  }
  idx -= 1048576;
  if (idx < 262144) {             // CW [1024][256]: W_ih cols 1.. | W1 cols 256..
    int n = idx >> 8, k = idx & 255;
    float v = 0.f;
    if (n < 768) { if (k < 208) v = W_ih[n*209 + 1 + k]; }
    else         { if (k < 208) v = W1[(n-768)*464 + 256 + k]; }
    CW[idx] = f2bf(v);
    return;
  }
  idx -= 262144;
  if (idx < 196608) { WhhB[idx] = f2bf(W_hh[idx]); return; }
  idx -= 196608;
  if (idx < 65536) { int n = idx>>8, k = idx&255; W1aB[idx] = f2bf(W1[n*464+k]); return; }
  idx -= 65536;
  if (idx < 65536) { W2B[idx] = f2bf(W2[idx]); return; }
  idx -= 65536;
  if (idx < 16384) {
    int n = idx >> 8;
    float v = 0.f;
    if (n < 60) v = W3[idx];
    W3pB[idx] = f2bf(v);
    return;
  }
  idx -= 16384;
  if (idx < 768) w0[idx] = W_ih[idx*209];
}

// ---- pre-GEMM: [4096 x 1024 x 256(pad)] -> gi (cols<768, +b_ih[+b_hh r,u]) / P1 (+b1) ----
__global__ __launch_bounds__(512) void k_pre(
    const unsigned short* __restrict__ A, const unsigned short* __restrict__ Bw,
    const float* __restrict__ b_ih, const float* __restrict__ b_hh,
    const float* __restrict__ b1,
    float* __restrict__ gi, float* __restrict__ P1) {
  __shared__ __align__(16) unsigned short As[128*64];
  __shared__ __align__(16) unsigned short Bs[128*64];
  int tid = threadIdx.x;
  int rb = blockIdx.x >> 3, cb = blockIdx.x & 7;
  long row0 = (long)rb * 128;
  int n0 = cb * 128;
  int wv = tid >> 6, lane = tid & 63;
  int lq = lane >> 4, l16 = lane & 15;
  int wrg = wv & 3, wcg = wv >> 2;
  f32x4 acc[2][4];
#pragma unroll
  for (int i = 0; i < 2; ++i)
#pragma unroll
    for (int j = 0; j < 4; ++j) acc[i][j] = (f32x4){0.f,0.f,0.f,0.f};
  for (int kb = 0; kb < 256; kb += 64) {
#pragma unroll
    for (int i = 0; i < 2; ++i) {
      int s = i*512 + tid;
      int r = s >> 3, cg = (s & 7) ^ (r & 7);
      *(uint4*)&As[s*8] = *(const uint4*)&A[(row0 + r)*256 + kb + cg*8];
      *(uint4*)&Bs[s*8] = *(const uint4*)&Bw[(long)(n0 + r)*256 + kb + cg*8];
    }
    __syncthreads();
#pragma unroll
    for (int kc = 0; kc < 2; ++kc) {
      int csel = kc*4 + lq;
      bf16x8 af[2];
#pragma unroll
      for (int rt = 0; rt < 2; ++rt) {
        int r = wrg*32 + rt*16 + l16;
        af[rt] = *(const bf16x8*)&As[r*64 + ((csel ^ (r & 7)))*8];
      }
#pragma unroll
      for (int ct = 0; ct < 4; ++ct) {
        int n = wcg*64 + ct*16 + l16;
        bf16x8 bfr = *(const bf16x8*)&Bs[n*64 + ((csel ^ (n & 7)))*8];
        acc[0][ct] = __builtin_amdgcn_mfma_f32_16x16x32_bf16(af[0], bfr, acc[0][ct], 0, 0, 0);
        acc[1][ct] = __builtin_amdgcn_mfma_f32_16x16x32_bf16(af[1], bfr, acc[1][ct], 0, 0, 0);
      }
    }
    __syncthreads();
  }
#pragma unroll
  for (int rt = 0; rt < 2; ++rt)
#pragma unroll
    for (int q = 0; q < 4; ++q) {
      long row = row0 + wrg*32 + rt*16 + lq*4 + q;
#pragma unroll
      for (int ct = 0; ct < 4; ++ct) {
        int n = n0 + wcg*64 + ct*16 + l16;
        float v = acc[rt][ct][q];
        if (n < 512)      gi[row*G3 + n] = v + b_ih[n] + b_hh[n];  // r,u: fold b_hh
        else if (n < 768) gi[row*G3 + n] = v + b_ih[n];            // n-gate: b_hh_n applied later
        else              P1[row*256 + (n-768)] = v + b1[n-768];
      }
    }
}

// ---- persistent GRU: 256 blocks x 16 rows, t-loop inside, Whh in registers ----
__global__ __launch_bounds__(512, 2) void k_gru(
    const float* __restrict__ z, const float* __restrict__ gi,
    const unsigned short* __restrict__ WhhB, const float* __restrict__ b_hh,
    const float* __restrict__ w0, unsigned short* __restrict__ hs) {
  __shared__ __align__(16) unsigned short hbf[16*256];  // bf16 h, swizzled chunks
  __shared__ float hf[16*260];                          // fp32 master (pad 260)
  __shared__ __align__(16) float gis[16*772];           // gi slice (pad 772)
  int tid = threadIdx.x;
  int wv = tid >> 6, lane = tid & 63;
  int lq = lane >> 4, l16 = lane & 15;
  int row0 = blockIdx.x * 16;
  // preload Whh fragments for this wave's 6 col-tiles (gates r,u,n x 2 tiles of 16)
  bf16x8 wf[6][8];
#pragma unroll
  for (int g = 0; g < 3; ++g)
#pragma unroll
    for (int tt = 0; tt < 2; ++tt)
#pragma unroll
      for (int ks = 0; ks < 8; ++ks) {
        int gcol = g*256 + wv*32 + tt*16 + l16;
        wf[g*2+tt][ks] = *(const bf16x8*)&WhhB[(long)gcol*256 + ks*32 + lq*8];
      }
  float w0v[6], bhn[2];
#pragma unroll
  for (int g = 0; g < 3; ++g)
#pragma unroll
    for (int tt = 0; tt < 2; ++tt)
      w0v[g*2+tt] = w0[g*256 + wv*32 + tt*16 + l16];
#pragma unroll
  for (int tt = 0; tt < 2; ++tt)
    bhn[tt] = b_hh[512 + wv*32 + tt*16 + l16];
  // stage gi slice into LDS (row-major, stride 772 dwords)
  for (int s = tid; s < 16*192; s += 512) {          // 192 float4 per row
    int r = s / 192, c4 = (s - r*192) * 4;
    *(float4*)&gis[r*772 + c4] = *(const float4*)&gi[(long)(row0 + r)*G3 + c4];
  }
  // h = 0
  for (int i = tid; i < 16*256; i += 512) hbf[i] = 0;
  for (int i = tid; i < 16*260; i += 512) hf[i] = 0.0f;
  __syncthreads();
#pragma unroll 1
  for (int t = 0; t < NCC; ++t) {
    f32x4 acc[6];
#pragma unroll
    for (int i = 0; i < 6; ++i) acc[i] = (f32x4){0.f,0.f,0.f,0.f};
#pragma unroll
    for (int ks = 0; ks < 8; ++ks) {
      int r = l16;
      int chunk = ks*4 + lq;
      bf16x8 af = *(const bf16x8*)&hbf[r*256 + ((chunk ^ (r & 7)))*8];
#pragma unroll
      for (int f = 0; f < 6; ++f)
        acc[f] = __builtin_amdgcn_mfma_f32_16x16x32_bf16(af, wf[f][ks], acc[f], 0, 0, 0);
    }
    __syncthreads();   // all A-reads done before h overwrite
    int tm = (t > 0) ? (t - 1) : 0;
    float zp[4];
#pragma unroll
    for (int q = 0; q < 4; ++q) {
      int row = row0 + lq*4 + q;
      float zv = z[row*64 + tm];
      zp[q] = (t == 0) ? -1.0f : zv;
    }
#pragma unroll
    for (int tt = 0; tt < 2; ++tt) {
      int hc = wv*32 + tt*16 + l16;
#pragma unroll
      for (int q = 0; q < 4; ++q) {
        int lrow = lq*4 + q;
        const float* gr = gis + lrow*772;
        float rr = sigm(gr[hc]       + zp[q]*w0v[tt]   + acc[tt][q]);
        float uu = sigm(gr[256+hc]   + zp[q]*w0v[2+tt] + acc[2+tt][q]);
        float nn = tanh_fast(gr[512+hc] + zp[q]*w0v[4+tt] + rr*(acc[4+tt][q] + bhn[tt]));
        float hp = hf[lrow*260 + hc];
        float hn = (1.0f - uu)*nn + uu*hp;
        hf[lrow*260 + hc] = hn;
        unsigned short hb = f2bf(hn);
        hbf[lrow*256 + ((hc >> 3) ^ (lrow & 7))*8 + (hc & 7)] = hb;
        hs[((long)(row0 + lrow)*64 + t)*256 + hc] = hb;
      }
    }
    __syncthreads();   // h writes visible before next step's reads
  }
}

// ---- MLP layer 1, in-place: Out = tanh(A @ W1a^T + P1[row>>6]) ----
__global__ __launch_bounds__(512) void k_l1(
    const unsigned short* __restrict__ A, const unsigned short* __restrict__ Bw,
    const float* __restrict__ P1, unsigned short* __restrict__ Out) {
  __shared__ __align__(16) unsigned short As[128*64];
  __shared__ __align__(16) unsigned short Bs[256*64];
  int tid = threadIdx.x;
  long row0 = (long)blockIdx.x * 128;
  int wv = tid >> 6, lane = tid & 63;
  int lq = lane >> 4, l16 = lane & 15;
  int wrg = wv & 3, wcg = wv >> 2;
  f32x4 acc[2][8];
#pragma unroll
  for (int i = 0; i < 2; ++i)
#pragma unroll
    for (int j = 0; j < 8; ++j) acc[i][j] = (f32x4){0.f,0.f,0.f,0.f};
  for (int kb = 0; kb < 256; kb += 64) {
#pragma unroll
    for (int i = 0; i < 2; ++i) {
      int s = i*512 + tid;
      int r = s >> 3, cg = (s & 7) ^ (r & 7);
      *(uint4*)&As[s*8] = *(const uint4*)&A[(row0 + r)*256 + kb + cg*8];
    }
#pragma unroll
    for (int i = 0; i < 4; ++i) {
      int s = i*512 + tid;
      int r = s >> 3, cg = (s & 7) ^ (r & 7);
      *(uint4*)&Bs[s*8] = *(const uint4*)&Bw[(long)r*256 + kb + cg*8];
    }
    __syncthreads();
#pragma unroll
    for (int kc = 0; kc < 2; ++kc) {
      int csel = kc*4 + lq;
      bf16x8 af[2];
#pragma unroll
      for (int rt = 0; rt < 2; ++rt) {
        int r = wrg*32 + rt*16 + l16;
        af[rt] = *(const bf16x8*)&As[r*64 + ((csel ^ (r & 7)))*8];
      }
#pragma unroll
      for (int ct = 0; ct < 8; ++ct) {
        int n = wcg*128 + ct*16 + l16;
        bf16x8 bfr = *(const bf16x8*)&Bs[n*64 + ((csel ^ (n & 7)))*8];
        acc[0][ct] = __builtin_amdgcn_mfma_f32_16x16x32_bf16(af[0], bfr, acc[0][ct], 0, 0, 0);
        acc[1][ct] = __builtin_amdgcn_mfma_f32_16x16x32_bf16(af[1], bfr, acc[1][ct], 0, 0, 0);
      }
    }
    __syncthreads();
  }
#pragma unroll
  for (int rt = 0; rt < 2; ++rt)
#pragma unroll
    for (int q = 0; q < 4; ++q) {
      long row = row0 + wrg*32 + rt*16 + lq*4 + q;
#pragma unroll
      for (int ct = 0; ct < 8; ++ct) {
        int n = wcg*128 + ct*16 + l16;
        float b = P1[(row >> 6)*256 + n];
        Out[row*256 + n] = f2bf(tanh_fast(acc[rt][ct][q] + b));
      }
    }
}

// ---- fused MLP layer2 + layer3 + mixture likelihood ----
__global__ __launch_bounds__(512) void k_l23(
    const unsigned short* __restrict__ A, const unsigned short* __restrict__ W2B,
    const float* __restrict__ b2, const unsigned short* __restrict__ W3pB,
    const float* __restrict__ b3, const float* __restrict__ z,
    float* __restrict__ ll) {
  __shared__ __align__(16) unsigned short As[128*64];
  __shared__ __align__(16) unsigned short Bs[256*64];
  __shared__ __align__(16) unsigned short h2s[128*256];
  int tid = threadIdx.x;
  long row0 = (long)blockIdx.x * 128;
  int wv = tid >> 6, lane = tid & 63;
  int lq = lane >> 4, l16 = lane & 15;
  int wrg = wv & 3, wcg = wv >> 2;
  f32x4 acc[2][8];
#pragma unroll
  for (int i = 0; i < 2; ++i)
#pragma unroll
    for (int j = 0; j < 8; ++j) acc[i][j] = (f32x4){0.f,0.f,0.f,0.f};
  for (int kb = 0; kb < 256; kb += 64) {
#pragma unroll
    for (int i = 0; i < 2; ++i) {
      int s = i*512 + tid;
      int r = s >> 3, cg = (s & 7) ^ (r & 7);
      *(uint4*)&As[s*8] = *(const uint4*)&A[(row0 + r)*256 + kb + cg*8];
    }
#pragma unroll
    for (int i = 0; i < 4; ++i) {
      int s = i*512 + tid;
      int r = s >> 3, cg = (s & 7) ^ (r & 7);
      *(uint4*)&Bs[s*8] = *(const uint4*)&W2B[(long)r*256 + kb + cg*8];
    }
    __syncthreads();
#pragma unroll
    for (int kc = 0; kc < 2; ++kc) {
      int csel = kc*4 + lq;
      bf16x8 af[2];
#pragma unroll
      for (int rt = 0; rt < 2; ++rt) {
        int r = wrg*32 + rt*16 + l16;
        af[rt] = *(const bf16x8*)&As[r*64 + ((csel ^ (r & 7)))*8];
      }
#pragma unroll
      for (int ct = 0; ct < 8; ++ct) {
        int n = wcg*128 + ct*16 + l16;
        bf16x8 bfr = *(const bf16x8*)&Bs[n*64 + ((csel ^ (n & 7)))*8];
        acc[0][ct] = __builtin_amdgcn_mfma_f32_16x16x32_bf16(af[0], bfr, acc[0][ct], 0, 0, 0);
        acc[1][ct] = __builtin_amdgcn_mfma_f32_16x16x32_bf16(af[1], bfr, acc[1][ct], 0, 0, 0);
      }
    }
    __syncthreads();
  }
  // h2 -> LDS (bf16, swizzled for A-side reads)
#pragma unroll
  for (int rt = 0; rt < 2; ++rt)
#pragma unroll
    for (int q = 0; q < 4; ++q) {
      int lr = wrg*32 + rt*16 + lq*4 + q;
#pragma unroll
      for (int ct = 0; ct < 8; ++ct) {
        int n = wcg*128 + ct*16 + l16;
        h2s[lr*256 + ((n >> 3) ^ (lr & 7))*8 + (n & 7)] =
            f2bf(tanh_fast(acc[rt][ct][q] + b2[n]));
      }
    }
  // stage W3p into Bs (64 x 256), swizzled
#pragma unroll
  for (int i = 0; i < 4; ++i) {
    int s = i*512 + tid;
    int r = s >> 5, cc = s & 31, cg = cc ^ (r & 7);
    *(uint4*)&Bs[r*256 + cg*8] = *(const uint4*)&W3pB[r*256 + cc*8];
  }
  __syncthreads();
  // stage 2: each wave computes its own 16 rows x 64 params
  f32x4 pacc[4];
#pragma unroll
  for (int j = 0; j < 4; ++j) pacc[j] = (f32x4){0.f,0.f,0.f,0.f};
#pragma unroll
  for (int ks = 0; ks < 8; ++ks) {
    int chunk = ks*4 + lq;
    int ar = wv*16 + l16;
    bf16x8 af = *(const bf16x8*)&h2s[ar*256 + ((chunk ^ (ar & 7)))*8];
#pragma unroll
    for (int ct = 0; ct < 4; ++ct) {
      int br = ct*16 + l16;
      bf16x8 bfr = *(const bf16x8*)&Bs[br*256 + ((chunk ^ (br & 7)))*8];
      pacc[ct] = __builtin_amdgcn_mfma_f32_16x16x32_bf16(af, bfr, pacc[ct], 0, 0, 0);
    }
  }
  // params to own LDS region (reuse h2s rows of this wave), stride 68 fp32
  float* Ps = (float*)&h2s[wv*16*256];
#pragma unroll
  for (int ct = 0; ct < 4; ++ct) {
    int n = ct*16 + l16;
    float b = (n < 60) ? b3[n] : 0.0f;
#pragma unroll
    for (int q = 0; q < 4; ++q)
      Ps[(lq*4 + q)*68 + n] = pacc[ct][q] + b;
  }
  // per-row likelihood (wave-internal; DS ordering within wave suffices)
  if (lane < 16) {
    long grow = row0 + wv*16 + lane;
    float zv = z[grow];
    const float* p = &Ps[lane*68];
    float mx1 = -1e30f;
#pragma unroll
    for (int i = 0; i < NK; ++i) mx1 = fmaxf(mx1, p[i]);
    float s1 = 0.0f;
#pragma unroll
    for (int i = 0; i < NK; ++i) s1 += __expf(p[i] - mx1);
    float lse1 = mx1 + __logf(s1);
    float a[NK];
    float mx2 = -1e30f;
#pragma unroll
    for (int i = 0; i < NK; ++i) {
      float lg = p[i], me = p[20+i], ls = p[40+i];
      float e = __expf(-ls);
      float d = (zv - me) * e;
      float ai = -0.5f*d*d - ls - 0.5f*LOG2PI + lg;
      a[i] = ai;
      mx2 = fmaxf(mx2, ai);
    }
    float s2 = 0.0f;
#pragma unroll
    for (int i = 0; i < NK; ++i) s2 += __expf(a[i] - mx2);
    float lse2 = mx2 + __logf(s2);
    ll[grow] = lse2 - lse1;
  }
}

// out[b] = sum_{t < S_b} ll[b,t]
__global__ __launch_bounds__(256) void k_final(const float* __restrict__ bv,
    const float* __restrict__ mv, const float* __restrict__ ll,
    float* __restrict__ out) {
  int tid = threadIdx.x;
  int wave = tid >> 6, lane = tid & 63;
  int b = blockIdx.x*4 + wave;
  float q = mv[b*64 + lane] * (1.0f - bv[b*64 + lane]);
  unsigned long long bal = __ballot(q > 0.5f);
  int S = __popcll(bal);
  float val = (lane < S) ? ll[(long)b*64 + lane] : 0.0f;
#pragma unroll
  for (int off = 32; off > 0; off >>= 1) val += __shfl_down(val, off);
  if (lane == 0) out[b] = val;
}

extern "C" void kernel_launch(void* const* d_in, const int* in_sizes, int n_in,
                              void* d_out, int out_size, void* d_ws, size_t ws_size,
                              hipStream_t stream) {
  const float* z    = (const float*)d_in[0];
  const float* c    = (const float*)d_in[1];
  const float* bv   = (const float*)d_in[2];
  const float* mv   = (const float*)d_in[3];
  const float* W_ih = (const float*)d_in[4];
  const float* W_hh = (const float*)d_in[5];
  const float* b_ih = (const float*)d_in[6];
  const float* b_hh = (const float*)d_in[7];
  const float* W1   = (const float*)d_in[8];
  const float* b1   = (const float*)d_in[9];
  const float* W2   = (const float*)d_in[10];
  const float* b2   = (const float*)d_in[11];
  const float* W3   = (const float*)d_in[12];
  const float* b3   = (const float*)d_in[13];
  float* out = (float*)d_out;

  char* p = (char*)d_ws;
  auto alloc = [&](size_t bytes) {
    char* q = p;
    p += (bytes + 255) & ~(size_t)255;
    return q;
  };
  unsigned short* cbmB = (unsigned short*)alloc((size_t)BATCH*256*2);
  unsigned short* CW   = (unsigned short*)alloc((size_t)1024*256*2);
  unsigned short* WhhB = (unsigned short*)alloc((size_t)G3*256*2);
  unsigned short* W1aB = (unsigned short*)alloc((size_t)256*256*2);
  unsigned short* W2B  = (unsigned short*)alloc((size_t)256*256*2);
  unsigned short* W3pB = (unsigned short*)alloc((size_t)64*256*2);
  float* w0 = (float*)alloc((size_t)G3*4);
  float* gi = (float*)alloc((size_t)BATCH*G3*4);
  float* P1 = (float*)alloc((size_t)BATCH*256*4);
  float* ll = (float*)alloc((size_t)NROW*4);
  unsigned short* hs = (unsigned short*)alloc((size_t)NROW*HDIM*2);

  k_cvtall<<<6468, 256, 0, stream>>>(c, bv, mv, W_ih, W_hh, W1, W2, W3,
                                     cbmB, CW, WhhB, W1aB, W2B, W3pB, w0);
  k_pre<<<256, 512, 0, stream>>>(cbmB, CW, b_ih, b_hh, b1, gi, P1);
  k_gru<<<256, 512, 0, stream>>>(z, gi, WhhB, b_hh, w0, hs);
  k_l1<<<NROW/128, 512, 0, stream>>>(hs, W1aB, P1, hs);
  k_l23<<<NROW/128, 512, 0, stream>>>(hs, W2B, b2, W3pB, b3, z, ll);
  k_final<<<BATCH/4, 256, 0, stream>>>(bv, mv, ll, out);
}